// Round 7
// baseline (387.986 us; speedup 1.0000x reference)
//
#include <hip/hip_runtime.h>

#define NN 50000
#define NEDGE 400000
#define MPAD 50048
#define NB 196  // scan blocks: 196*256 = 50176 >= NN
constexpr float LN_EPS = 1e-5f;

typedef __attribute__((ext_vector_type(8))) short bf16x8;
typedef __attribute__((ext_vector_type(4))) float f32x4;
typedef __attribute__((ext_vector_type(8))) unsigned short ushort8v;

__device__ __forceinline__ unsigned short f2bf(float f) {  // RNE
  unsigned int u = __float_as_uint(f);
  u += 0x7FFFu + ((u >> 16) & 1u);
  return (unsigned short)(u >> 16);
}
__device__ __forceinline__ float bf2f(unsigned short u) {
  return __uint_as_float(((unsigned int)u) << 16);
}

// ---------------- prep: weight transpose->bf16, x->bf16, zero cnt (one launch) ----------------
__global__ __launch_bounds__(256) void k_prep(
    const float* __restrict__ W1, const float* __restrict__ W2,
    const float* __restrict__ W3, const float* __restrict__ W4,
    unsigned short* __restrict__ Wt1, unsigned short* __restrict__ Wt2,
    unsigned short* __restrict__ Wt3, unsigned short* __restrict__ Wt4,
    const float* __restrict__ x, unsigned short* __restrict__ xB,
    int* __restrict__ cnt) {
  const int b = blockIdx.x;
  const int n = threadIdx.x;
  if (b < 128) {                       // W1: K=128,N=256
    Wt1[(size_t)n * 128 + b] = f2bf(W1[(size_t)b * 256 + n]);
  } else if (b < 384) {                // W2: K=256,N=256
    const int k = b - 128;
    Wt2[(size_t)n * 256 + k] = f2bf(W2[(size_t)k * 256 + n]);
  } else if (b < 640) {                // W3
    const int k = b - 384;
    Wt3[(size_t)n * 256 + k] = f2bf(W3[(size_t)k * 256 + n]);
  } else if (b < 896) {                // W4: K=256,N=128
    const int k = b - 640;
    if (n < 128) Wt4[(size_t)n * 256 + k] = f2bf(W4[(size_t)k * 128 + n]);
  } else if (b < 7146) {               // x -> bf16, one float4 per thread
    const int i = (b - 896) * 256 + n;
    float4 v = reinterpret_cast<const float4*>(x)[i];
    ushort4 o; o.x = f2bf(v.x); o.y = f2bf(v.y); o.z = f2bf(v.z); o.w = f2bf(v.w);
    reinterpret_cast<ushort4*>(xB)[i] = o;
  } else {                             // zero cnt
    const int i = (b - 7146) * 256 + n;
    if (i < NN) cnt[i] = 0;
  }
}

// ---------------- CSR build ----------------
__global__ void k_count(const int* __restrict__ dst, int* __restrict__ cnt) {
  int e = blockIdx.x * blockDim.x + threadIdx.x;
  if (e < NEDGE) atomicAdd(&cnt[dst[e]], 1);
}

// block partial sums of cnt (+ fused dinv)
__global__ __launch_bounds__(256) void k_bsum(const int* __restrict__ cnt,
                                              int* __restrict__ bsum,
                                              float* __restrict__ dinv) {
  const int i = blockIdx.x * 256 + threadIdx.x;
  int v = 0;
  if (i < NN) {
    v = cnt[i];
    dinv[i] = rsqrtf((float)v + 1.0f);
  }
  int s = v;
#pragma unroll
  for (int off = 32; off > 0; off >>= 1) s += __shfl_xor(s, off);
  __shared__ int wsum[4];
  if ((threadIdx.x & 63) == 0) wsum[threadIdx.x >> 6] = s;
  __syncthreads();
  if (threadIdx.x == 0) bsum[blockIdx.x] = wsum[0] + wsum[1] + wsum[2] + wsum[3];
}

// rowptr build: every block scans bsum (196 entries) in LDS, then per-block scan of cnt.
// Writes rowptr AND a mutable cursor copy for k_fill.
__global__ __launch_bounds__(256) void k_bapply(const int* __restrict__ cnt,
                                                const int* __restrict__ bsum,
                                                int* __restrict__ rowptr,
                                                int* __restrict__ cursor) {
  __shared__ int sOff[NB];
  __shared__ int wsum[4], woff[4];
  const int t = threadIdx.x;
  const int lane = t & 63, wid = t >> 6;

  {
    int v = (t < NB) ? bsum[t] : 0;
    int inc = v;
    for (int off = 1; off < 64; off <<= 1) {
      int y = __shfl_up(inc, off);
      if (lane >= off) inc += y;
    }
    if (lane == 63) wsum[wid] = inc;
    __syncthreads();
    if (t == 0) {
      int run = 0;
      for (int w = 0; w < 4; ++w) { woff[w] = run; run += wsum[w]; }
    }
    __syncthreads();
    if (t < NB) sOff[t] = woff[wid] + inc - v;
  }
  __syncthreads();

  const int i = blockIdx.x * 256 + t;
  int v = (i < NN) ? cnt[i] : 0;
  int inc = v;
  for (int off = 1; off < 64; off <<= 1) {
    int y = __shfl_up(inc, off);
    if (lane >= off) inc += y;
  }
  if (lane == 63) wsum[wid] = inc;
  __syncthreads();
  if (t == 0) {
    int run = 0;
    for (int w = 0; w < 4; ++w) { woff[w] = run; run += wsum[w]; }
  }
  __syncthreads();
  if (i < NN) {
    const int rp = sOff[blockIdx.x] + woff[wid] + inc - v;
    rowptr[i] = rp;
    cursor[i] = rp;
  }
  if (blockIdx.x == 0 && t == 0) rowptr[NN] = NEDGE;
}

// fill CSR with (src, weight) pairs; weight = dinv[src]*dinv[dst]
__global__ void k_fill(const int* __restrict__ src, const int* __restrict__ dst,
                       const float* __restrict__ dinv, int* __restrict__ cursor,
                       int2* __restrict__ eidx2) {
  int e = blockIdx.x * blockDim.x + threadIdx.x;
  if (e >= NEDGE) return;
  const int d = dst[e];
  const int s = src[e];
  const int p = atomicAdd(&cursor[d], 1);
  eidx2[p] = make_int2(s, __float_as_int(dinv[s] * dinv[d]));
}

// ---------------- fused gather + MFMA GEMM + bias/LN/ReLU ----------------
// block: 4 waves, 64 output rows. Gather phase: each wave aggregates its 16 nodes
// (NPW concurrent, LPN=K/8 lanes each, 16B/lane) into registers, converts to bf16,
// writes swizzled LDS A-tile. GEMM phase: identical to k_mgemm with fused LN+ReLU.
template<int K, int N>
__global__ __launch_bounds__(256) void k_gg(
    const int* __restrict__ rowptr, const int2* __restrict__ eidx2,
    const float* __restrict__ dinv, const unsigned short* __restrict__ hIn,
    const unsigned short* __restrict__ Bt, const float* __restrict__ bias,
    const float* __restrict__ gamma, const float* __restrict__ beta,
    unsigned short* __restrict__ out) {
  constexpr int LPN = K / 8;       // lanes per node (8 bf16 = 16B per lane)
  constexpr int NPW = 64 / LPN;    // nodes concurrent per wave
  constexpr int NT = N / 64;       // 16-col tiles per wave
  constexpr int KS = K / 32;       // k-steps
  __shared__ __align__(16) unsigned short As[64 * K];

  const int tid = threadIdx.x;
  const int lane = tid & 63;
  const int w = tid >> 6;
  const int m0 = blockIdx.x * 64;
  const int sub = lane / LPN;
  const int slane = lane % LPN;

  // ---- gather phase ----
  for (int it = 0; it < 16 / NPW; ++it) {
    const int rr = w * 16 + it * NPW + sub;   // row within tile
    const int n = m0 + rr;
    const bool valid = n < NN;
    int e = 0, end = 0;
    float dn = 0.f;
    if (valid) { dn = dinv[n]; e = rowptr[n]; end = rowptr[n + 1]; }
    float acc[8];
    ushort8v r0 = (ushort8v)0, r1 = (ushort8v)0, r2 = (ushort8v)0, r3 = (ushort8v)0;
    if (valid) r0 = *reinterpret_cast<const ushort8v*>(hIn + (size_t)n * K + slane * 8);
    const float sw = dn * dn;
#pragma unroll
    for (int j = 0; j < 8; ++j) acc[j] = bf2f(r0[j]) * sw;
    r0 = (ushort8v)0;

    while (__ballot(e < end)) {
      float w0 = 0.f, w1 = 0.f, w2 = 0.f, w3 = 0.f;
      if (e < end) {
        const int2 p = eidx2[e];
        w0 = __int_as_float(p.y);
        r0 = *reinterpret_cast<const ushort8v*>(hIn + (size_t)p.x * K + slane * 8);
      }
      if (e + 1 < end) {
        const int2 p = eidx2[e + 1];
        w1 = __int_as_float(p.y);
        r1 = *reinterpret_cast<const ushort8v*>(hIn + (size_t)p.x * K + slane * 8);
      }
      if (e + 2 < end) {
        const int2 p = eidx2[e + 2];
        w2 = __int_as_float(p.y);
        r2 = *reinterpret_cast<const ushort8v*>(hIn + (size_t)p.x * K + slane * 8);
      }
      if (e + 3 < end) {
        const int2 p = eidx2[e + 3];
        w3 = __int_as_float(p.y);
        r3 = *reinterpret_cast<const ushort8v*>(hIn + (size_t)p.x * K + slane * 8);
      }
#pragma unroll
      for (int j = 0; j < 8; ++j)
        acc[j] += w0 * bf2f(r0[j]) + w1 * bf2f(r1[j]) + w2 * bf2f(r2[j]) + w3 * bf2f(r3[j]);
      e += 4;
    }

    ushort8v ob;
#pragma unroll
    for (int j = 0; j < 8; ++j) ob[j] = f2bf(acc[j]);
    int boff = (rr * K + slane * 8) * 2;
    boff ^= (rr & 7) << 4;
    *reinterpret_cast<ushort8v*>((char*)As + boff) = ob;
  }
  __syncthreads();

  // ---- GEMM phase ----
  f32x4 acc[4][NT];
#pragma unroll
  for (int mt = 0; mt < 4; ++mt)
#pragma unroll
    for (int nt = 0; nt < NT; ++nt) acc[mt][nt] = (f32x4){0.f, 0.f, 0.f, 0.f};

  const int nw0 = w * (N / 4);
  const int arow = lane & 15;
  const int kgrp = (lane >> 4) * 8;

  for (int ks = 0; ks < KS; ++ks) {
    bf16x8 af[4];
#pragma unroll
    for (int mt = 0; mt < 4; ++mt) {
      const int r = mt * 16 + arow;
      int boff = (r * K + ks * 32 + kgrp) * 2;
      boff ^= (r & 7) << 4;
      af[mt] = *reinterpret_cast<const bf16x8*>((const char*)As + boff);
    }
    bf16x8 bfr[NT];
#pragma unroll
    for (int nt = 0; nt < NT; ++nt) {
      const int n = nw0 + nt * 16 + arow;
      bfr[nt] = *reinterpret_cast<const bf16x8*>(Bt + (size_t)n * K + ks * 32 + kgrp);
    }
#pragma unroll
    for (int mt = 0; mt < 4; ++mt)
#pragma unroll
      for (int nt = 0; nt < NT; ++nt)
        acc[mt][nt] = __builtin_amdgcn_mfma_f32_16x16x32_bf16(af[mt], bfr[nt], acc[mt][nt], 0, 0, 0);
  }

  const int g = lane >> 4;
  const int cl = lane & 15;

  float gv[NT], bev[NT];
#pragma unroll
  for (int nt = 0; nt < NT; ++nt) {
    const int c = nw0 + nt * 16 + cl;
    const float bv = bias[c];
    gv[nt] = gamma[c];
    bev[nt] = beta[c];
#pragma unroll
    for (int mt = 0; mt < 4; ++mt)
#pragma unroll
      for (int reg = 0; reg < 4; ++reg) acc[mt][nt][reg] += bv;
  }
  __shared__ float sS[4][64];
  __shared__ float sQ[4][64];
  float ps[4][4], pq[4][4];
#pragma unroll
  for (int mt = 0; mt < 4; ++mt) {
#pragma unroll
    for (int reg = 0; reg < 4; ++reg) {
      float s = 0.f, q = 0.f;
#pragma unroll
      for (int nt = 0; nt < NT; ++nt) {
        const float v = acc[mt][nt][reg];
        s += v; q = fmaf(v, v, q);
      }
#pragma unroll
      for (int off = 1; off < 16; off <<= 1) {
        s += __shfl_xor(s, off);
        q += __shfl_xor(q, off);
      }
      ps[mt][reg] = s; pq[mt][reg] = q;
    }
  }
  if (cl == 0) {
#pragma unroll
    for (int mt = 0; mt < 4; ++mt)
#pragma unroll
      for (int reg = 0; reg < 4; ++reg) {
        sS[w][mt * 16 + g * 4 + reg] = ps[mt][reg];
        sQ[w][mt * 16 + g * 4 + reg] = pq[mt][reg];
      }
  }
  __syncthreads();
#pragma unroll
  for (int mt = 0; mt < 4; ++mt) {
#pragma unroll
    for (int reg = 0; reg < 4; ++reg) {
      const int rr = mt * 16 + g * 4 + reg;
      const int r = m0 + rr;
      const float S = sS[0][rr] + sS[1][rr] + sS[2][rr] + sS[3][rr];
      const float Q = sQ[0][rr] + sQ[1][rr] + sQ[2][rr] + sQ[3][rr];
      const float mean = S * (1.0f / N);
      const float var = Q * (1.0f / N) - mean * mean;
      const float inv = rsqrtf(var + LN_EPS);
      if (r < NN) {
#pragma unroll
        for (int nt = 0; nt < NT; ++nt) {
          const int c = nw0 + nt * 16 + cl;
          const float o = fmaxf((acc[mt][nt][reg] - mean) * inv * gv[nt] + bev[nt], 0.f);
          out[(size_t)r * N + c] = f2bf(o);
        }
      }
    }
  }
}

// ---------------- plain MFMA GEMM (layer-4 transform, bf16 out) ----------------
template<int K, int N>
__global__ __launch_bounds__(256) void k_mgemm(const unsigned short* __restrict__ A,
                                               const unsigned short* __restrict__ Bt,
                                               unsigned short* __restrict__ out) {
  constexpr int NT = N / 64;
  constexpr int KS = K / 32;
  __shared__ __align__(16) unsigned short As[64 * K];

  const int tid = threadIdx.x;
  const int lane = tid & 63;
  const int w = tid >> 6;
  const int m0 = blockIdx.x * 64;

#pragma unroll
  for (int i = 0; i < KS; ++i) {
    const int o = (i * 256 + tid) * 16;
    const int row = o / (2 * K);
    const int inb = o % (2 * K);
    uint4 val = *reinterpret_cast<const uint4*>(
        (const char*)A + (size_t)(m0 + row) * (2 * K) + inb);
    const int dsto = o ^ ((row & 7) << 4);
    *reinterpret_cast<uint4*>((char*)As + dsto) = val;
  }
  __syncthreads();

  f32x4 acc[4][NT];
#pragma unroll
  for (int mt = 0; mt < 4; ++mt)
#pragma unroll
    for (int nt = 0; nt < NT; ++nt) acc[mt][nt] = (f32x4){0.f, 0.f, 0.f, 0.f};

  const int nw0 = w * (N / 4);
  const int arow = lane & 15;
  const int kgrp = (lane >> 4) * 8;

  for (int ks = 0; ks < KS; ++ks) {
    bf16x8 af[4];
#pragma unroll
    for (int mt = 0; mt < 4; ++mt) {
      const int r = mt * 16 + arow;
      int boff = (r * K + ks * 32 + kgrp) * 2;
      boff ^= (r & 7) << 4;
      af[mt] = *reinterpret_cast<const bf16x8*>((const char*)As + boff);
    }
    bf16x8 bfr[NT];
#pragma unroll
    for (int nt = 0; nt < NT; ++nt) {
      const int n = nw0 + nt * 16 + arow;
      bfr[nt] = *reinterpret_cast<const bf16x8*>(Bt + (size_t)n * K + ks * 32 + kgrp);
    }
#pragma unroll
    for (int mt = 0; mt < 4; ++mt)
#pragma unroll
      for (int nt = 0; nt < NT; ++nt)
        acc[mt][nt] = __builtin_amdgcn_mfma_f32_16x16x32_bf16(af[mt], bfr[nt], acc[mt][nt], 0, 0, 0);
  }

  const int g = lane >> 4;
  const int cl = lane & 15;
#pragma unroll
  for (int mt = 0; mt < 4; ++mt) {
#pragma unroll
    for (int nt = 0; nt < NT; ++nt) {
      const int c = nw0 + nt * 16 + cl;
#pragma unroll
      for (int reg = 0; reg < 4; ++reg) {
        const int r = m0 + mt * 16 + g * 4 + reg;
        if (r < NN) out[(size_t)r * N + c] = f2bf(acc[mt][nt][reg]);
      }
    }
  }
}

// ---------------- final gather + fused bias+LN (F=128), fp32 out ----------------
__global__ __launch_bounds__(256) void k_gather_final(
    const int* __restrict__ rowptr, const int2* __restrict__ eidx2,
    const float* __restrict__ dinv, const unsigned short* __restrict__ h,
    float* __restrict__ outv, const float* __restrict__ bias,
    const float* __restrict__ gamma, const float* __restrict__ beta) {
  constexpr int F = 128, LPN = 16, NPW = 4;
  const int tid = threadIdx.x;
  const int lane = tid & 63;
  const int sub = lane / LPN;
  const int slane = lane % LPN;
  const int n = blockIdx.x * (4 * NPW) + (tid >> 6) * NPW + sub;
  const bool valid = n < NN;

  int e = 0, end = 0;
  float dn = 0.f;
  if (valid) {
    dn = dinv[n];
    e = rowptr[n];
    end = rowptr[n + 1];
  }

  float acc[8];
  ushort8v r0 = (ushort8v)0, r1 = (ushort8v)0, r2 = (ushort8v)0, r3 = (ushort8v)0;
  if (valid) r0 = *reinterpret_cast<const ushort8v*>(h + (size_t)n * F + slane * 8);
  const float sw = dn * dn;
#pragma unroll
  for (int j = 0; j < 8; ++j) acc[j] = bf2f(r0[j]) * sw;
  r0 = (ushort8v)0;

  while (__ballot(e < end)) {
    float w0 = 0.f, w1 = 0.f, w2 = 0.f, w3 = 0.f;
    if (e < end) {
      const int2 p = eidx2[e];
      w0 = __int_as_float(p.y);
      r0 = *reinterpret_cast<const ushort8v*>(h + (size_t)p.x * F + slane * 8);
    }
    if (e + 1 < end) {
      const int2 p = eidx2[e + 1];
      w1 = __int_as_float(p.y);
      r1 = *reinterpret_cast<const ushort8v*>(h + (size_t)p.x * F + slane * 8);
    }
    if (e + 2 < end) {
      const int2 p = eidx2[e + 2];
      w2 = __int_as_float(p.y);
      r2 = *reinterpret_cast<const ushort8v*>(h + (size_t)p.x * F + slane * 8);
    }
    if (e + 3 < end) {
      const int2 p = eidx2[e + 3];
      w3 = __int_as_float(p.y);
      r3 = *reinterpret_cast<const ushort8v*>(h + (size_t)p.x * F + slane * 8);
    }
#pragma unroll
    for (int j = 0; j < 8; ++j)
      acc[j] += w0 * bf2f(r0[j]) + w1 * bf2f(r1[j]) + w2 * bf2f(r2[j]) + w3 * bf2f(r3[j]);
    e += 4;
  }

  if (!valid) return;

  const float4 b0 = *reinterpret_cast<const float4*>(bias + slane * 8);
  const float4 b1 = *reinterpret_cast<const float4*>(bias + slane * 8 + 4);
  acc[0] += b0.x; acc[1] += b0.y; acc[2] += b0.z; acc[3] += b0.w;
  acc[4] += b1.x; acc[5] += b1.y; acc[6] += b1.z; acc[7] += b1.w;
  float s = 0.f, q = 0.f;
#pragma unroll
  for (int j = 0; j < 8; ++j) { s += acc[j]; q = fmaf(acc[j], acc[j], q); }
#pragma unroll
  for (int off = 1; off < 16; off <<= 1) {
    s += __shfl_xor(s, off);
    q += __shfl_xor(q, off);
  }
  const float mean = s * (1.0f / 128.0f);
  const float var = q * (1.0f / 128.0f) - mean * mean;
  const float inv = rsqrtf(var + LN_EPS);
  const float4 g0 = *reinterpret_cast<const float4*>(gamma + slane * 8);
  const float4 g1 = *reinterpret_cast<const float4*>(gamma + slane * 8 + 4);
  const float4 e0 = *reinterpret_cast<const float4*>(beta + slane * 8);
  const float4 e1 = *reinterpret_cast<const float4*>(beta + slane * 8 + 4);
  float4 o0, o1;
  o0.x = (acc[0] - mean) * inv * g0.x + e0.x;
  o0.y = (acc[1] - mean) * inv * g0.y + e0.y;
  o0.z = (acc[2] - mean) * inv * g0.z + e0.z;
  o0.w = (acc[3] - mean) * inv * g0.w + e0.w;
  o1.x = (acc[4] - mean) * inv * g1.x + e1.x;
  o1.y = (acc[5] - mean) * inv * g1.y + e1.y;
  o1.z = (acc[6] - mean) * inv * g1.z + e1.z;
  o1.w = (acc[7] - mean) * inv * g1.w + e1.w;
  float* out = outv + (size_t)n * 128 + slane * 8;
  *reinterpret_cast<float4*>(out) = o0;
  *reinterpret_cast<float4*>(out + 4) = o1;
}

extern "C" void kernel_launch(void* const* d_in, const int* in_sizes, int n_in,
                              void* d_out, int out_size, void* d_ws, size_t ws_size,
                              hipStream_t stream) {
  const float* x   = (const float*)d_in[0];
  const int*   ei  = (const int*)d_in[1];
  const float* W1  = (const float*)d_in[2];
  const float* b1  = (const float*)d_in[3];
  const float* W2  = (const float*)d_in[4];
  const float* b2  = (const float*)d_in[5];
  const float* W3  = (const float*)d_in[6];
  const float* b3  = (const float*)d_in[7];
  const float* W4  = (const float*)d_in[8];
  const float* b4  = (const float*)d_in[9];
  const float* g1  = (const float*)d_in[10];
  const float* be1 = (const float*)d_in[11];
  const float* g2  = (const float*)d_in[12];
  const float* be2 = (const float*)d_in[13];
  const float* g3  = (const float*)d_in[14];
  const float* be3 = (const float*)d_in[15];
  const float* g4  = (const float*)d_in[16];
  const float* be4 = (const float*)d_in[17];

  const int* src = ei;
  const int* dst = ei + NEDGE;

  char* ws = (char*)d_ws;
  int*   cnt    = (int*)(ws + 0);              // NN ints
  int*   cursor = (int*)(ws + 204800);         // NN ints
  int*   rowptr = (int*)(ws + 409600);         // NN+1 ints
  float* dinv   = (float*)(ws + 614400);       // NN floats
  int*   bsum   = (int*)(ws + 819200);         // NB ints
  int2*  eidx2  = (int2*)(ws + 827392);        // NEDGE int2 (3.2MB)
  unsigned short* Wt1 = (unsigned short*)(ws + 4030464);   // 256x128
  unsigned short* Wt2 = (unsigned short*)(ws + 4096000);   // 256x256
  unsigned short* Wt3 = (unsigned short*)(ws + 4227072);   // 256x256
  unsigned short* Wt4 = (unsigned short*)(ws + 4358144);   // 128x256
  unsigned short* xB  = (unsigned short*)(ws + 4423680);   // MPAD x 128 bf16
  unsigned short* hA  = (unsigned short*)(ws + 17235968);  // MPAD x 256 bf16
  unsigned short* hB  = (unsigned short*)(ws + 42860544);  // MPAD x 256 bf16
  unsigned short* t4B = (unsigned short*)(ws + 68485120);  // MPAD x 128 bf16
  float* out = (float*)d_out;

  const int MB = (NN + 63) / 64;  // 782

  // prep (weights+x conversion, cnt zero) + CSR build
  k_prep<<<7342, 256, 0, stream>>>(W1, W2, W3, W4, Wt1, Wt2, Wt3, Wt4, x, xB, cnt);
  k_count<<<(NEDGE + 255) / 256, 256, 0, stream>>>(dst, cnt);
  k_bsum<<<NB, 256, 0, stream>>>(cnt, bsum, dinv);
  k_bapply<<<NB, 256, 0, stream>>>(cnt, bsum, rowptr, cursor);
  k_fill<<<(NEDGE + 255) / 256, 256, 0, stream>>>(src, dst, dinv, cursor, eidx2);

  // ---- Layers 1-3: fused gather + GEMM + bias/LN/ReLU ----
  k_gg<128, 256><<<MB, 256, 0, stream>>>(rowptr, eidx2, dinv, xB, Wt1, b1, g1, be1, hA);
  k_gg<256, 256><<<MB, 256, 0, stream>>>(rowptr, eidx2, dinv, hA, Wt2, b2, g2, be2, hB);
  k_gg<256, 256><<<MB, 256, 0, stream>>>(rowptr, eidx2, dinv, hB, Wt3, b3, g3, be3, hA);

  // ---- Layer 4: transform (256->128) -> gather + fused bias+LN into d_out ----
  k_mgemm<256, 128><<<MB, 256, 0, stream>>>(hA, Wt4, t4B);
  k_gather_final<<<(NN + 15) / 16, 256, 0, stream>>>(rowptr, eidx2, dinv, t4B, out, b4, g4, be4);
}

// Round 8
// 287.427 us; speedup vs baseline: 1.3499x; 1.3499x over previous
//
#include <hip/hip_runtime.h>

#define NN 50000
#define NEDGE 400000
#define MPAD 50048
#define NB 196  // scan blocks: 196*256 = 50176 >= NN
constexpr float LN_EPS = 1e-5f;

typedef __attribute__((ext_vector_type(8))) short bf16x8;
typedef __attribute__((ext_vector_type(4))) float f32x4;
typedef __attribute__((ext_vector_type(8))) unsigned short ushort8v;

__device__ __forceinline__ unsigned short f2bf(float f) {  // RNE
  unsigned int u = __float_as_uint(f);
  u += 0x7FFFu + ((u >> 16) & 1u);
  return (unsigned short)(u >> 16);
}
__device__ __forceinline__ float bf2f(unsigned short u) {
  return __uint_as_float(((unsigned int)u) << 16);
}

// ---------------- prep: weight transpose->bf16, x->bf16, zero cnt (one launch) ----------------
__global__ __launch_bounds__(256) void k_prep(
    const float* __restrict__ W1, const float* __restrict__ W2,
    const float* __restrict__ W3, const float* __restrict__ W4,
    unsigned short* __restrict__ Wt1, unsigned short* __restrict__ Wt2,
    unsigned short* __restrict__ Wt3, unsigned short* __restrict__ Wt4,
    const float* __restrict__ x, unsigned short* __restrict__ xB,
    int* __restrict__ cnt) {
  const int b = blockIdx.x;
  const int n = threadIdx.x;
  if (b < 128) {                       // W1: K=128,N=256
    Wt1[(size_t)n * 128 + b] = f2bf(W1[(size_t)b * 256 + n]);
  } else if (b < 384) {                // W2: K=256,N=256
    const int k = b - 128;
    Wt2[(size_t)n * 256 + k] = f2bf(W2[(size_t)k * 256 + n]);
  } else if (b < 640) {                // W3
    const int k = b - 384;
    Wt3[(size_t)n * 256 + k] = f2bf(W3[(size_t)k * 256 + n]);
  } else if (b < 896) {                // W4: K=256,N=128
    const int k = b - 640;
    if (n < 128) Wt4[(size_t)n * 256 + k] = f2bf(W4[(size_t)k * 128 + n]);
  } else if (b < 7146) {               // x -> bf16, one float4 per thread
    const int i = (b - 896) * 256 + n;
    float4 v = reinterpret_cast<const float4*>(x)[i];
    ushort4 o; o.x = f2bf(v.x); o.y = f2bf(v.y); o.z = f2bf(v.z); o.w = f2bf(v.w);
    reinterpret_cast<ushort4*>(xB)[i] = o;
  } else {                             // zero cnt
    const int i = (b - 7146) * 256 + n;
    if (i < NN) cnt[i] = 0;
  }
}

// ---------------- CSR build ----------------
__global__ void k_count(const int* __restrict__ dst, int* __restrict__ cnt) {
  int e = blockIdx.x * blockDim.x + threadIdx.x;
  if (e < NEDGE) atomicAdd(&cnt[dst[e]], 1);
}

// block partial sums of cnt (+ fused dinv)
__global__ __launch_bounds__(256) void k_bsum(const int* __restrict__ cnt,
                                              int* __restrict__ bsum,
                                              float* __restrict__ dinv) {
  const int i = blockIdx.x * 256 + threadIdx.x;
  int v = 0;
  if (i < NN) {
    v = cnt[i];
    dinv[i] = rsqrtf((float)v + 1.0f);
  }
  int s = v;
#pragma unroll
  for (int off = 32; off > 0; off >>= 1) s += __shfl_xor(s, off);
  __shared__ int wsum[4];
  if ((threadIdx.x & 63) == 0) wsum[threadIdx.x >> 6] = s;
  __syncthreads();
  if (threadIdx.x == 0) bsum[blockIdx.x] = wsum[0] + wsum[1] + wsum[2] + wsum[3];
}

// rowptr build: every block scans bsum (196 entries) in LDS, then per-block scan of cnt.
// Writes rowptr AND a mutable cursor copy for k_fill.
__global__ __launch_bounds__(256) void k_bapply(const int* __restrict__ cnt,
                                                const int* __restrict__ bsum,
                                                int* __restrict__ rowptr,
                                                int* __restrict__ cursor) {
  __shared__ int sOff[NB];
  __shared__ int wsum[4], woff[4];
  const int t = threadIdx.x;
  const int lane = t & 63, wid = t >> 6;

  {
    int v = (t < NB) ? bsum[t] : 0;
    int inc = v;
    for (int off = 1; off < 64; off <<= 1) {
      int y = __shfl_up(inc, off);
      if (lane >= off) inc += y;
    }
    if (lane == 63) wsum[wid] = inc;
    __syncthreads();
    if (t == 0) {
      int run = 0;
      for (int w = 0; w < 4; ++w) { woff[w] = run; run += wsum[w]; }
    }
    __syncthreads();
    if (t < NB) sOff[t] = woff[wid] + inc - v;
  }
  __syncthreads();

  const int i = blockIdx.x * 256 + t;
  int v = (i < NN) ? cnt[i] : 0;
  int inc = v;
  for (int off = 1; off < 64; off <<= 1) {
    int y = __shfl_up(inc, off);
    if (lane >= off) inc += y;
  }
  if (lane == 63) wsum[wid] = inc;
  __syncthreads();
  if (t == 0) {
    int run = 0;
    for (int w = 0; w < 4; ++w) { woff[w] = run; run += wsum[w]; }
  }
  __syncthreads();
  if (i < NN) {
    const int rp = sOff[blockIdx.x] + woff[wid] + inc - v;
    rowptr[i] = rp;
    cursor[i] = rp;
  }
  if (blockIdx.x == 0 && t == 0) rowptr[NN] = NEDGE;
}

// fill CSR with (src, weight) pairs; weight = dinv[src]*dinv[dst]
__global__ void k_fill(const int* __restrict__ src, const int* __restrict__ dst,
                       const float* __restrict__ dinv, int* __restrict__ cursor,
                       int2* __restrict__ eidx2) {
  int e = blockIdx.x * blockDim.x + threadIdx.x;
  if (e >= NEDGE) return;
  const int d = dst[e];
  const int s = src[e];
  const int p = atomicAdd(&cursor[d], 1);
  eidx2[p] = make_int2(s, __float_as_int(dinv[s] * dinv[d]));
}

// ---------------- gather aggregation (CSR), multi-node waves, 8-wide unroll ----------------
// NPW nodes per wave; each node served by LPN=64/NPW lanes, 8 elems (16B) per lane.
// MODE 0: bf16 out.  MODE 1: fp32 out with fused bias+LN (F=128 final layer).
template<int F, int NPW, int MODE>
__global__ __launch_bounds__(256) void k_gather(
    const int* __restrict__ rowptr, const int2* __restrict__ eidx2,
    const float* __restrict__ dinv, const unsigned short* __restrict__ h,
    void* __restrict__ outv, const float* __restrict__ bias,
    const float* __restrict__ gamma, const float* __restrict__ beta) {
  constexpr int LPN = 64 / NPW;
  static_assert(F / LPN == 8, "16B per lane");
  const int tid = threadIdx.x;
  const int lane = tid & 63;
  const int sub = lane / LPN;
  const int slane = lane % LPN;
  const int n = blockIdx.x * (4 * NPW) + (tid >> 6) * NPW + sub;
  const bool valid = n < NN;

  int e = 0, end = 0;
  float dn = 0.f;
  if (valid) {
    dn = dinv[n];
    e = rowptr[n];
    end = rowptr[n + 1];
  }

  float acc[8];
  ushort8v r[8];
#pragma unroll
  for (int u = 0; u < 8; ++u) r[u] = (ushort8v)0;
  {
    ushort8v r0 = (ushort8v)0;
    if (valid) r0 = *reinterpret_cast<const ushort8v*>(h + (size_t)n * F + slane * 8);
    const float sw = dn * dn;
#pragma unroll
    for (int j = 0; j < 8; ++j) acc[j] = bf2f(r0[j]) * sw;
  }

  while (__ballot(e < end)) {
    float wgt[8];
#pragma unroll
    for (int u = 0; u < 8; ++u) {
      wgt[u] = 0.f;
      if (e + u < end) {
        const int2 p = eidx2[e + u];
        wgt[u] = __int_as_float(p.y);
        r[u] = *reinterpret_cast<const ushort8v*>(h + (size_t)p.x * F + slane * 8);
      }
    }
#pragma unroll
    for (int u = 0; u < 8; ++u)
#pragma unroll
      for (int j = 0; j < 8; ++j)
        acc[j] += wgt[u] * bf2f(r[u][j]);
    e += 8;
  }

  if (!valid) return;

  if constexpr (MODE == 0) {
    ushort8v o;
#pragma unroll
    for (int j = 0; j < 8; ++j) o[j] = f2bf(acc[j]);
    *reinterpret_cast<ushort8v*>((unsigned short*)outv + (size_t)n * F + slane * 8) = o;
  } else {
    // fused bias + LN over F=128 (16 lanes per row)
    const float4 b0 = *reinterpret_cast<const float4*>(bias + slane * 8);
    const float4 b1 = *reinterpret_cast<const float4*>(bias + slane * 8 + 4);
    acc[0] += b0.x; acc[1] += b0.y; acc[2] += b0.z; acc[3] += b0.w;
    acc[4] += b1.x; acc[5] += b1.y; acc[6] += b1.z; acc[7] += b1.w;
    float s = 0.f, q = 0.f;
#pragma unroll
    for (int j = 0; j < 8; ++j) { s += acc[j]; q = fmaf(acc[j], acc[j], q); }
#pragma unroll
    for (int off = 1; off < 16; off <<= 1) {
      s += __shfl_xor(s, off);
      q += __shfl_xor(q, off);
    }
    const float mean = s * (1.0f / 128.0f);
    const float var = q * (1.0f / 128.0f) - mean * mean;
    const float inv = rsqrtf(var + LN_EPS);
    const float4 g0 = *reinterpret_cast<const float4*>(gamma + slane * 8);
    const float4 g1 = *reinterpret_cast<const float4*>(gamma + slane * 8 + 4);
    const float4 e0 = *reinterpret_cast<const float4*>(beta + slane * 8);
    const float4 e1 = *reinterpret_cast<const float4*>(beta + slane * 8 + 4);
    float4 o0, o1;
    o0.x = (acc[0] - mean) * inv * g0.x + e0.x;
    o0.y = (acc[1] - mean) * inv * g0.y + e0.y;
    o0.z = (acc[2] - mean) * inv * g0.z + e0.z;
    o0.w = (acc[3] - mean) * inv * g0.w + e0.w;
    o1.x = (acc[4] - mean) * inv * g1.x + e1.x;
    o1.y = (acc[5] - mean) * inv * g1.y + e1.y;
    o1.z = (acc[6] - mean) * inv * g1.z + e1.z;
    o1.w = (acc[7] - mean) * inv * g1.w + e1.w;
    float* out = (float*)outv + (size_t)n * 128 + slane * 8;
    *reinterpret_cast<float4*>(out) = o0;
    *reinterpret_cast<float4*>(out + 4) = o1;
  }
}

// ---------------- MFMA GEMM, optional fused bias+LN+ReLU epilogue ----------------
// block: 4 waves, 64 rows; wave w owns cols [w*N/4, (w+1)*N/4)
template<int K, int N, bool LNFUSE>
__global__ __launch_bounds__(256) void k_mgemm(const unsigned short* __restrict__ A,
                                               const unsigned short* __restrict__ Bt,
                                               const float* __restrict__ bias,
                                               const float* __restrict__ gamma,
                                               const float* __restrict__ beta,
                                               unsigned short* __restrict__ out) {
  constexpr int NT = N / 64;   // 16-col tiles per wave
  constexpr int KS = K / 32;   // k-steps
  __shared__ __align__(16) unsigned short As[64 * K];

  const int tid = threadIdx.x;
  const int lane = tid & 63;
  const int w = tid >> 6;
  const int m0 = blockIdx.x * 64;

  // stage A tile into LDS with XOR swizzle on 16B slots
#pragma unroll
  for (int i = 0; i < KS; ++i) {
    const int o = (i * 256 + tid) * 16;
    const int row = o / (2 * K);
    const int inb = o % (2 * K);
    uint4 val = *reinterpret_cast<const uint4*>(
        (const char*)A + (size_t)(m0 + row) * (2 * K) + inb);
    const int dsto = o ^ ((row & 7) << 4);
    *reinterpret_cast<uint4*>((char*)As + dsto) = val;
  }
  __syncthreads();

  f32x4 acc[4][NT];
#pragma unroll
  for (int mt = 0; mt < 4; ++mt)
#pragma unroll
    for (int nt = 0; nt < NT; ++nt) acc[mt][nt] = (f32x4){0.f, 0.f, 0.f, 0.f};

  const int nw0 = w * (N / 4);
  const int arow = lane & 15;
  const int kgrp = (lane >> 4) * 8;

  for (int ks = 0; ks < KS; ++ks) {
    bf16x8 af[4];
#pragma unroll
    for (int mt = 0; mt < 4; ++mt) {
      const int r = mt * 16 + arow;
      int boff = (r * K + ks * 32 + kgrp) * 2;
      boff ^= (r & 7) << 4;
      af[mt] = *reinterpret_cast<const bf16x8*>((const char*)As + boff);
    }
    bf16x8 bfr[NT];
#pragma unroll
    for (int nt = 0; nt < NT; ++nt) {
      const int n = nw0 + nt * 16 + arow;
      bfr[nt] = *reinterpret_cast<const bf16x8*>(Bt + (size_t)n * K + ks * 32 + kgrp);
    }
#pragma unroll
    for (int mt = 0; mt < 4; ++mt)
#pragma unroll
      for (int nt = 0; nt < NT; ++nt)
        acc[mt][nt] = __builtin_amdgcn_mfma_f32_16x16x32_bf16(af[mt], bfr[nt], acc[mt][nt], 0, 0, 0);
  }

  const int g = lane >> 4;       // 16-lane group: rows g*4..g*4+3 (+16*mt)
  const int cl = lane & 15;      // col within 16-tile

  if constexpr (LNFUSE) {
    float gv[NT], bev[NT];
#pragma unroll
    for (int nt = 0; nt < NT; ++nt) {
      const int c = nw0 + nt * 16 + cl;
      const float bv = bias[c];
      gv[nt] = gamma[c];
      bev[nt] = beta[c];
#pragma unroll
      for (int mt = 0; mt < 4; ++mt)
#pragma unroll
        for (int reg = 0; reg < 4; ++reg) acc[mt][nt][reg] += bv;
    }
    __shared__ float sS[4][64];
    __shared__ float sQ[4][64];
    float ps[4][4], pq[4][4];
#pragma unroll
    for (int mt = 0; mt < 4; ++mt) {
#pragma unroll
      for (int reg = 0; reg < 4; ++reg) {
        float s = 0.f, q = 0.f;
#pragma unroll
        for (int nt = 0; nt < NT; ++nt) {
          const float v = acc[mt][nt][reg];
          s += v; q = fmaf(v, v, q);
        }
#pragma unroll
        for (int off = 1; off < 16; off <<= 1) {
          s += __shfl_xor(s, off);
          q += __shfl_xor(q, off);
        }
        ps[mt][reg] = s; pq[mt][reg] = q;
      }
    }
    if (cl == 0) {
#pragma unroll
      for (int mt = 0; mt < 4; ++mt)
#pragma unroll
        for (int reg = 0; reg < 4; ++reg) {
          sS[w][mt * 16 + g * 4 + reg] = ps[mt][reg];
          sQ[w][mt * 16 + g * 4 + reg] = pq[mt][reg];
        }
    }
    __syncthreads();
#pragma unroll
    for (int mt = 0; mt < 4; ++mt) {
#pragma unroll
      for (int reg = 0; reg < 4; ++reg) {
        const int rr = mt * 16 + g * 4 + reg;
        const int r = m0 + rr;
        const float S = sS[0][rr] + sS[1][rr] + sS[2][rr] + sS[3][rr];
        const float Q = sQ[0][rr] + sQ[1][rr] + sQ[2][rr] + sQ[3][rr];
        const float mean = S * (1.0f / N);
        const float var = Q * (1.0f / N) - mean * mean;
        const float inv = rsqrtf(var + LN_EPS);
        if (r < NN) {
#pragma unroll
          for (int nt = 0; nt < NT; ++nt) {
            const int c = nw0 + nt * 16 + cl;
            const float o = fmaxf((acc[mt][nt][reg] - mean) * inv * gv[nt] + bev[nt], 0.f);
            out[(size_t)r * N + c] = f2bf(o);
          }
        }
      }
    }
  } else {
#pragma unroll
    for (int mt = 0; mt < 4; ++mt) {
#pragma unroll
      for (int nt = 0; nt < NT; ++nt) {
        const int c = nw0 + nt * 16 + cl;
#pragma unroll
        for (int reg = 0; reg < 4; ++reg) {
          const int r = m0 + mt * 16 + g * 4 + reg;
          if (r < NN) out[(size_t)r * N + c] = f2bf(acc[mt][nt][reg]);
        }
      }
    }
  }
}

extern "C" void kernel_launch(void* const* d_in, const int* in_sizes, int n_in,
                              void* d_out, int out_size, void* d_ws, size_t ws_size,
                              hipStream_t stream) {
  const float* x   = (const float*)d_in[0];
  const int*   ei  = (const int*)d_in[1];
  const float* W1  = (const float*)d_in[2];
  const float* b1  = (const float*)d_in[3];
  const float* W2  = (const float*)d_in[4];
  const float* b2  = (const float*)d_in[5];
  const float* W3  = (const float*)d_in[6];
  const float* b3  = (const float*)d_in[7];
  const float* W4  = (const float*)d_in[8];
  const float* b4  = (const float*)d_in[9];
  const float* g1  = (const float*)d_in[10];
  const float* be1 = (const float*)d_in[11];
  const float* g2  = (const float*)d_in[12];
  const float* be2 = (const float*)d_in[13];
  const float* g3  = (const float*)d_in[14];
  const float* be3 = (const float*)d_in[15];
  const float* g4  = (const float*)d_in[16];
  const float* be4 = (const float*)d_in[17];

  const int* src = ei;
  const int* dst = ei + NEDGE;

  char* ws = (char*)d_ws;
  int*   cnt    = (int*)(ws + 0);              // NN ints
  int*   cursor = (int*)(ws + 204800);         // NN ints
  int*   rowptr = (int*)(ws + 409600);         // NN+1 ints
  float* dinv   = (float*)(ws + 614400);       // NN floats
  int*   bsum   = (int*)(ws + 819200);         // NB ints
  int2*  eidx2  = (int2*)(ws + 827392);        // NEDGE int2 (3.2MB)
  unsigned short* Wt1 = (unsigned short*)(ws + 4030464);   // 256x128
  unsigned short* Wt2 = (unsigned short*)(ws + 4096000);   // 256x256
  unsigned short* Wt3 = (unsigned short*)(ws + 4227072);   // 256x256
  unsigned short* Wt4 = (unsigned short*)(ws + 4358144);   // 128x256
  unsigned short* xB  = (unsigned short*)(ws + 4423680);   // MPAD x 128 bf16
  unsigned short* aggB = (unsigned short*)(ws + 17235968); // MPAD x 256 bf16
  unsigned short* hB   = (unsigned short*)(ws + 42860544); // MPAD x 256 bf16
  unsigned short* t4B  = (unsigned short*)(ws + 68485120); // MPAD x 128 bf16
  float* out = (float*)d_out;

  const int MB = (NN + 63) / 64;  // 782

  // prep (weights+x conversion, cnt zero) + CSR build
  k_prep<<<7342, 256, 0, stream>>>(W1, W2, W3, W4, Wt1, Wt2, Wt3, Wt4, x, xB, cnt);
  k_count<<<(NEDGE + 255) / 256, 256, 0, stream>>>(dst, cnt);
  k_bsum<<<NB, 256, 0, stream>>>(cnt, bsum, dinv);
  k_bapply<<<NB, 256, 0, stream>>>(cnt, bsum, rowptr, cursor);
  k_fill<<<(NEDGE + 255) / 256, 256, 0, stream>>>(src, dst, dinv, cursor, eidx2);

  // ---- Layer 1 ----
  k_gather<128, 4, 0><<<(NN + 15) / 16, 256, 0, stream>>>(rowptr, eidx2, dinv, xB, aggB, nullptr, nullptr, nullptr);
  k_mgemm<128, 256, true><<<MB, 256, 0, stream>>>(aggB, Wt1, b1, g1, be1, hB);

  // ---- Layer 2 ----
  k_gather<256, 2, 0><<<(NN + 7) / 8, 256, 0, stream>>>(rowptr, eidx2, dinv, hB, aggB, nullptr, nullptr, nullptr);
  k_mgemm<256, 256, true><<<MB, 256, 0, stream>>>(aggB, Wt2, b2, g2, be2, hB);

  // ---- Layer 3 ----
  k_gather<256, 2, 0><<<(NN + 7) / 8, 256, 0, stream>>>(rowptr, eidx2, dinv, hB, aggB, nullptr, nullptr, nullptr);
  k_mgemm<256, 256, true><<<MB, 256, 0, stream>>>(aggB, Wt3, b3, g3, be3, hB);

  // ---- Layer 4: transform (256->128) -> gather + fused bias+LN into d_out ----
  k_mgemm<256, 128, false><<<MB, 256, 0, stream>>>(hB, Wt4, nullptr, nullptr, nullptr, t4B);
  k_gather<128, 4, 1><<<(NN + 15) / 16, 256, 0, stream>>>(rowptr, eidx2, dinv, t4B, out, b4, g4, be4);
}